// Round 9
// baseline (148.148 us; speedup 1.0000x reference)
//
#include <hip/hip_runtime.h>

#define NTOK 1024
#define DDIM 128

typedef _Float16 f16;
typedef _Float16 f16x2v __attribute__((ext_vector_type(2)));
typedef _Float16 f16x4 __attribute__((ext_vector_type(4)));
typedef _Float16 f16x8 __attribute__((ext_vector_type(8)));
typedef float f32x16 __attribute__((ext_vector_type(16)));
typedef unsigned int uint;
typedef uint uint2v __attribute__((ext_vector_type(2)));
typedef long i64;

union PFrag {
  float f[4];
  uint u[4];
  f16x8 h;
};

#define AS1 __attribute__((address_space(1)))
#define AS3 __attribute__((address_space(3)))
#define NLOG2E -1.44269504f

// ---------------- fused prepass (unchanged, verified) ------------------------
__global__ __launch_bounds__(256) void prep_fused(
    const float* __restrict__ x, const float* __restrict__ beta,
    unsigned char* __restrict__ x8n, f16* __restrict__ xhT,
    uint* __restrict__ betaTp) {
  __shared__ __align__(16) char psm[128 * 132 * 2];
  int bx = blockIdx.x;
  int t = threadIdx.x;
  if (bx < 512) {
    f16* sT = (f16*)psm;  // [128][132]
    int bc = bx & 63;
    int nt = bx >> 6;
    int n0 = nt * 128;
    const float4* xv = (const float4*)(x + ((size_t)bc * NTOK + n0) * DDIM);
#pragma unroll
    for (int k = 0; k < 16; ++k) {
      int idx = t + 256 * k;
      int row = idx >> 5;
      int c4 = idx & 31;
      float4 v = xv[(size_t)row * 32 + c4];
      float ss = v.x * v.x + v.y * v.y + v.z * v.z + v.w * v.w;
      ss += __shfl_xor(ss, 1);
      ss += __shfl_xor(ss, 2);
      ss += __shfl_xor(ss, 4);
      ss += __shfl_xor(ss, 8);
      ss += __shfl_xor(ss, 16);
      float rn = (ss > 0.f) ? rsqrtf(ss) : 0.f;
      int p01 = __builtin_amdgcn_cvt_pk_fp8_f32(v.x * rn, v.y * rn, 0, false);
      int p03 = __builtin_amdgcn_cvt_pk_fp8_f32(v.z * rn, v.w * rn, p01, true);
      *(int*)(x8n + ((size_t)bc * NTOK + n0 + row) * DDIM + c4 * 4) = p03;
      f16x4 hv = {(f16)v.x, (f16)v.y, (f16)v.z, (f16)v.w};
      *(f16x4*)(sT + row * 132 + c4 * 4) = hv;
    }
    __syncthreads();
    int dr = t >> 1;
    int half = t & 1;
    f16* dst = xhT + ((size_t)bc * DDIM + dr) * NTOK + n0 + 64 * half;
#pragma unroll
    for (int s = 0; s < 8; ++s) {
      f16x8 tmp;
#pragma unroll
      for (int j = 0; j < 8; ++j)
        tmp[j] = sT[(64 * half + s * 8 + j) * 132 + dr];
      *(f16x8*)(dst + s * 8) = tmp;
    }
  } else {
    float(*s)[65] = (float(*)[65])psm;
    int bb = bx - 512;
    int bi = bb & 15;   // i tile
    int bj = bb >> 4;   // m tile
    int r = t >> 4;
    int c4 = (t & 15) * 4;
#pragma unroll
    for (int rr = 0; rr < 64; rr += 16) {
      float4 v = *(const float4*)(beta + (size_t)(bi * 64 + r + rr) * NTOK +
                                  bj * 64 + c4);
      s[r + rr][c4] = v.x;
      s[r + rr][c4 + 1] = v.y;
      s[r + rr][c4 + 2] = v.z;
      s[r + rr][c4 + 3] = v.w;
    }
    __syncthreads();
    int il = t & 63;
#pragma unroll
    for (int rr = 0; rr < 8; ++rr) {
      int m2 = (t >> 6) + 4 * rr;  // 0..31
      float b0 = s[il][2 * m2] * NLOG2E;
      float b1 = s[il][2 * m2 + 1] * NLOG2E;
      uint u = __builtin_bit_cast(uint, __builtin_amdgcn_cvt_pkrtz(b0, b1));
      betaTp[(size_t)(bj * 32 + m2) * NTOK + bi * 64 + il] = u;
    }
  }
}

// ---------------- main ------------------------------------------------------
// R7 geometry + 2-STAGE SOFTWARE PIPELINE: iteration mi computes GEMM1(mi)
// into sN while sigmoid+GEMM2 process tile mi-1 from sC (previous iter's s).
// This BREAKS the per-iteration serial chain GEMM1->sigmoid->GEMM2: sigmoid's
// VALU/trans ops no longer depend on this iteration's MFMAs, so the compiler
// can interleave them into the MFMA shadow (and GEMM2's MFMAs fill sigmoid's
// trans stalls). Costs: +16 VGPR (sA/sB), sXmT triple-buffered (lifetime 2
// iters) -> LDS 64KB, launch_bounds(512,2) (VGPR cap 256: NO SPILL possible).
// Math and accumulation order bit-identical to R7.
__global__ __launch_bounds__(512, 2) void cos_att_main(
    const unsigned char* __restrict__ x8n, const f16* __restrict__ xhT,
    const uint* __restrict__ betaTp, float* __restrict__ out) {
  // [0,16K): sXm8 x2 (8K each)   [16K,64K): sXmT x3 (16K each)
  __shared__ __align__(16) char smem[65536];
  int bx = blockIdx.x;
  int bc = bx & 63;
  int qp = bx >> 6;  // 0..7
  int q0 = qp * 128;

  int t = threadIdx.x;
  int lane = t & 63;
  int w = t >> 6;  // 0..7
  int l31 = lane & 31;
  int hi = lane >> 5;
  int i_str = (w >> 1) * 32;  // 0,32,64,96
  int m_str = (w & 1) * 32;

  // Xq B-frags (fp8) for this wave's 32 q rows (16 VGPRs)
  i64 xq8[8];
  {
    const unsigned char* base =
        x8n + ((size_t)bc * NTOK + q0 + i_str + l31) * DDIM + hi * 8;
#pragma unroll
    for (int kk = 0; kk < 8; ++kk) xq8[kk] = *(const i64*)(base + kk * 16);
  }

  auto stage8 = [&](int mi) {  // sXm8 tile mi -> slot mi&1
    int m0 = mi * 64;
    char* ldsm8 = smem + (mi & 1) * 8192;
    int r = t >> 3;
    int cp = t & 7;
    const unsigned char* gp =
        x8n + ((size_t)bc * NTOK + m0 + r) * DDIM + ((cp ^ (r & 7)) * 16);
    __builtin_amdgcn_global_load_lds((const AS1 uint*)gp,
                                     (AS3 uint*)(ldsm8 + t * 16), 16, 0, 0);
  };
  auto stageT = [&](int mi) {  // sXmT tile mi -> slot mi%3
    int m0 = mi * 64;
    char* ldst = smem + 16384 + (mi % 3) * 16384;
    int lr = lane >> 3;
    int cp = lane & 7;
    const f16* gb = xhT + (size_t)bc * DDIM * NTOK + m0;
#pragma unroll
    for (int j = 0; j < 2; ++j) {
      int d = 16 * w + 8 * j + lr;
      int g = cp ^ (d & 7);
      const f16* gp = gb + (size_t)d * NTOK + g * 8;
      __builtin_amdgcn_global_load_lds(
          (const AS1 uint*)gp, (AS3 uint*)(ldst + (16 * w + 8 * j) * 128),
          16, 0, 0);
    }
  };

  // beta f16-pair loads for tile mi (consumed by NEXT iter's sigmoid)
  uint bvp[8];
  auto loadBeta = [&](int mi) {
    const uint* bbase =
        betaTp + (size_t)((mi * 64 + m_str) >> 1) * NTOK + q0 + i_str + l31;
#pragma unroll
    for (int rp = 0; rp < 8; ++rp) {
      int m2l = (rp & 1) + 4 * (rp >> 1) + 2 * hi;
      bvp[rp] = bbase[(size_t)m2l * NTOK];
    }
  };

  auto gemm1 = [&](int mi, f32x16& sN) {  // reads sXm8 slot mi&1
    const char* ldsm8 = smem + (mi & 1) * 8192;
#pragma unroll
    for (int z = 0; z < 16; ++z) sN[z] = 0.f;
    int rA = m_str + l31;
    const char* rowA = ldsm8 + rA * 128;
    int rx = rA & 7;
    __builtin_amdgcn_s_setprio(1);
#pragma unroll
    for (int kk = 0; kk < 8; ++kk) {
      i64 a = *(const i64*)(rowA + ((kk ^ rx) * 16) + hi * 8);
      sN = __builtin_amdgcn_mfma_f32_32x32x16_fp8_fp8(a, xq8[kk], sN, 0, 0, 0);
    }
    __builtin_amdgcn_s_setprio(0);
  };

  auto sigmoidP = [&](const f32x16& sC, PFrag& b0, PFrag& b1) {
    uint pku[8];
#pragma unroll
    for (int rp = 0; rp < 8; ++rp) {
      f16x2v bh = __builtin_bit_cast(f16x2v, bvp[rp]);
      // betaTp pre-scaled by -log2(e): P = rcp(1 + exp2(b'*cos))
      float e0 = __builtin_amdgcn_exp2f((float)bh[0] * sC[2 * rp]);
      float e1 = __builtin_amdgcn_exp2f((float)bh[1] * sC[2 * rp + 1]);
      float p0 = __builtin_amdgcn_rcpf(1.0f + e0);
      float p1 = __builtin_amdgcn_rcpf(1.0f + e1);
      pku[rp] = __builtin_bit_cast(uint, __builtin_amdgcn_cvt_pkrtz(p0, p1));
    }
    uint2v r02 = __builtin_amdgcn_permlane32_swap(pku[0], pku[2], false, false);
    uint2v r13 = __builtin_amdgcn_permlane32_swap(pku[1], pku[3], false, false);
    uint2v r46 = __builtin_amdgcn_permlane32_swap(pku[4], pku[6], false, false);
    uint2v r57 = __builtin_amdgcn_permlane32_swap(pku[5], pku[7], false, false);
    b0.u[0] = r02.x;
    b0.u[1] = r13.x;
    b0.u[2] = r02.y;
    b0.u[3] = r13.y;
    b1.u[0] = r46.x;
    b1.u[1] = r57.x;
    b1.u[2] = r46.y;
    b1.u[3] = r57.y;
  };

  f32x16 o[4];
#pragma unroll
  for (int dt = 0; dt < 4; ++dt)
#pragma unroll
    for (int z = 0; z < 16; ++z) o[dt][z] = 0.f;

  auto gemm2 = [&](int mi, PFrag& b0, PFrag& b1) {  // reads sXmT slot mi%3
    const char* ldst = smem + 16384 + (mi % 3) * 16384;
    __builtin_amdgcn_s_setprio(1);
#pragma unroll
    for (int dt = 0; dt < 4; ++dt) {
      int d = dt * 32 + l31;
      const char* rowT = ldst + d * 128;
      int dx = d & 7;
      int g0 = (m_str >> 3) + hi;
      f16x8 a0 = *(const f16x8*)(rowT + ((g0 ^ dx) * 16));
      f16x8 a1 = *(const f16x8*)(rowT + (((g0 + 2) ^ dx) * 16));
      o[dt] = __builtin_amdgcn_mfma_f32_32x32x16_f16(a0, b0.h, o[dt], 0, 0, 0);
      o[dt] = __builtin_amdgcn_mfma_f32_32x32x16_f16(a1, b1.h, o[dt], 0, 0, 0);
    }
    __builtin_amdgcn_s_setprio(0);
  };

  // ---- pipeline prologue: fill stage for tile 0 ----
  stage8(0);
  stageT(0);
  f32x16 sA, sB;
  __syncthreads();  // slot0 DMAs drained
  gemm1(0, sA);     // s(0) -> sA
  stage8(1);
  stageT(1);
  loadBeta(0);  // for body(1)'s sigmoid

  // ---- steady state: body(mi) = GEMM1(mi) + {sigmoid,GEMM2}(mi-1) ----
  auto body = [&](int mi, const f32x16& sC, f32x16& sN) {
    __syncthreads();  // stage DMAs issued last iter drained
    gemm1(mi, sN);
    if (mi < 15) {
      stage8(mi + 1);
      stageT(mi + 1);
    }
    PFrag b0, b1;
    sigmoidP(sC, b0, b1);  // tile mi-1 (independent of gemm1(mi))
    gemm2(mi - 1, b0, b1);
    loadBeta(mi);  // for next body's sigmoid (WAR after sigmoid read)
  };
  for (int mt = 0; mt < 7; ++mt) {
    body(2 * mt + 1, sA, sB);
    body(2 * mt + 2, sB, sA);
  }
  body(15, sA, sB);  // reads s(14)=sA, writes s(15)=sB

  // ---- pipeline tail: finish tile 15 ----
  {
    PFrag b0, b1;
    sigmoidP(sB, b0, b1);  // bvp = beta(15), loaded in body(15)
    gemm2(15, b0, b1);     // slot 15%3=0, staged iter 14, untouched since
  }

  // epilogue: per 64-row pass, m-half pair-reduce + transpose via LDS.
  // sO logical [64][128] f32, 16B-chunk XOR by (row&7): float4 I/O, <=4-way.
  float* sO = (float*)smem;  // 32 KB < 64K
  int ig = w >> 1;
  int mh = w & 1;
  int row = (ig & 1) * 32 + l31;
  int rb = row & 7;
#pragma unroll
  for (int p = 0; p < 2; ++p) {
    __syncthreads();
    if ((ig >> 1) == p && mh == 0) {
#pragma unroll
      for (int dt = 0; dt < 4; ++dt)
#pragma unroll
        for (int r4 = 0; r4 < 4; ++r4) {
          int c = dt * 8 + 2 * r4 + hi;  // 16B chunk: d = 4*c .. 4*c+3
          float4 v = {o[dt][4 * r4], o[dt][4 * r4 + 1], o[dt][4 * r4 + 2],
                      o[dt][4 * r4 + 3]};
          *(float4*)(sO + row * 128 + ((c ^ rb) * 4)) = v;
        }
    }
    __syncthreads();
    if ((ig >> 1) == p && mh == 1) {
#pragma unroll
      for (int dt = 0; dt < 4; ++dt)
#pragma unroll
        for (int r4 = 0; r4 < 4; ++r4) {
          int c = dt * 8 + 2 * r4 + hi;
          float4* pp = (float4*)(sO + row * 128 + ((c ^ rb) * 4));
          float4 v = *pp;
          v.x += o[dt][4 * r4];
          v.y += o[dt][4 * r4 + 1];
          v.z += o[dt][4 * r4 + 2];
          v.w += o[dt][4 * r4 + 3];
          *pp = v;
        }
    }
    __syncthreads();
    float* og = out + ((size_t)bc * NTOK + q0 + 64 * p) * DDIM;
#pragma unroll
    for (int k = 0; k < 4; ++k) {
      int idx = t + 512 * k;
      int r = idx >> 5;
      int c4 = idx & 31;
      *(float4*)(og + (size_t)r * DDIM + c4 * 4) =
          *(const float4*)(sO + r * 128 + ((c4 ^ (r & 7)) * 4));
    }
  }
}

extern "C" void kernel_launch(void* const* d_in, const int* in_sizes, int n_in,
                              void* d_out, int out_size, void* d_ws,
                              size_t ws_size, hipStream_t stream) {
  const float* x = (const float*)d_in[0];
  const float* beta = (const float*)d_in[1];
  float* out = (float*)d_out;

  char* ws = (char*)d_ws;
  unsigned char* x8n = (unsigned char*)ws;  // 8 MB
  f16* xhT = (f16*)(ws + (8 << 20));        // 16 MB
  uint* betaTp = (uint*)(ws + (24 << 20));  // 2 MB

  prep_fused<<<768, 256, 0, stream>>>(x, beta, x8n, xhT, betaTp);
  cos_att_main<<<512, 512, 0, stream>>>(x8n, xhT, betaTp, out);
}

// Round 10
// 145.171 us; speedup vs baseline: 1.0205x; 1.0205x over previous
//
#include <hip/hip_runtime.h>

#define NTOK 1024
#define DDIM 128

typedef _Float16 f16;
typedef _Float16 f16x2v __attribute__((ext_vector_type(2)));
typedef _Float16 f16x4 __attribute__((ext_vector_type(4)));
typedef _Float16 f16x8 __attribute__((ext_vector_type(8)));
typedef float f32x16 __attribute__((ext_vector_type(16)));
typedef unsigned int uint;
typedef uint uint2v __attribute__((ext_vector_type(2)));
typedef long i64;

union PFrag {
  float f[4];
  uint u[4];
  f16x8 h;
};

#define AS1 __attribute__((address_space(1)))
#define AS3 __attribute__((address_space(3)))
#define NLOG2E -1.44269504f

// ---------------- fused prepass (unchanged, verified) ------------------------
__global__ __launch_bounds__(256) void prep_fused(
    const float* __restrict__ x, const float* __restrict__ beta,
    unsigned char* __restrict__ x8n, f16* __restrict__ xhT,
    uint* __restrict__ betaTp) {
  __shared__ __align__(16) char psm[128 * 132 * 2];
  int bx = blockIdx.x;
  int t = threadIdx.x;
  if (bx < 512) {
    f16* sT = (f16*)psm;  // [128][132]
    int bc = bx & 63;
    int nt = bx >> 6;
    int n0 = nt * 128;
    const float4* xv = (const float4*)(x + ((size_t)bc * NTOK + n0) * DDIM);
#pragma unroll
    for (int k = 0; k < 16; ++k) {
      int idx = t + 256 * k;
      int row = idx >> 5;
      int c4 = idx & 31;
      float4 v = xv[(size_t)row * 32 + c4];
      float ss = v.x * v.x + v.y * v.y + v.z * v.z + v.w * v.w;
      ss += __shfl_xor(ss, 1);
      ss += __shfl_xor(ss, 2);
      ss += __shfl_xor(ss, 4);
      ss += __shfl_xor(ss, 8);
      ss += __shfl_xor(ss, 16);
      float rn = (ss > 0.f) ? rsqrtf(ss) : 0.f;
      int p01 = __builtin_amdgcn_cvt_pk_fp8_f32(v.x * rn, v.y * rn, 0, false);
      int p03 = __builtin_amdgcn_cvt_pk_fp8_f32(v.z * rn, v.w * rn, p01, true);
      *(int*)(x8n + ((size_t)bc * NTOK + n0 + row) * DDIM + c4 * 4) = p03;
      f16x4 hv = {(f16)v.x, (f16)v.y, (f16)v.z, (f16)v.w};
      *(f16x4*)(sT + row * 132 + c4 * 4) = hv;
    }
    __syncthreads();
    int dr = t >> 1;
    int half = t & 1;
    f16* dst = xhT + ((size_t)bc * DDIM + dr) * NTOK + n0 + 64 * half;
#pragma unroll
    for (int s = 0; s < 8; ++s) {
      f16x8 tmp;
#pragma unroll
      for (int j = 0; j < 8; ++j)
        tmp[j] = sT[(64 * half + s * 8 + j) * 132 + dr];
      *(f16x8*)(dst + s * 8) = tmp;
    }
  } else {
    float(*s)[65] = (float(*)[65])psm;
    int bb = bx - 512;
    int bi = bb & 15;   // i tile
    int bj = bb >> 4;   // m tile
    int r = t >> 4;
    int c4 = (t & 15) * 4;
#pragma unroll
    for (int rr = 0; rr < 64; rr += 16) {
      float4 v = *(const float4*)(beta + (size_t)(bi * 64 + r + rr) * NTOK +
                                  bj * 64 + c4);
      s[r + rr][c4] = v.x;
      s[r + rr][c4 + 1] = v.y;
      s[r + rr][c4 + 2] = v.z;
      s[r + rr][c4 + 3] = v.w;
    }
    __syncthreads();
    int il = t & 63;
#pragma unroll
    for (int rr = 0; rr < 8; ++rr) {
      int m2 = (t >> 6) + 4 * rr;  // 0..31
      float b0 = s[il][2 * m2] * NLOG2E;
      float b1 = s[il][2 * m2 + 1] * NLOG2E;
      uint u = __builtin_bit_cast(uint, __builtin_amdgcn_cvt_pkrtz(b0, b1));
      betaTp[(size_t)(bj * 32 + m2) * NTOK + bi * 64 + il] = u;
    }
  }
}

// ---------------- main ------------------------------------------------------
// R7 champion (54.8us) with CONFLICT-FREE LDS LAYOUTS. Old layout: [rows][128B]
// -> bank = f(16B-slot only), 32 lanes reading 32 rows at the same slot class
// = 4-way conflict on every A-frag read (5.37M conflict cycles/dispatch,
// ~8.7us/CU, matches 524k*4 + 524k*8 predicted). New: paired-row [rows/2][256B]
// with 4-bit swizzle slot = (2*chunk + row_parity) ^ (R&15): b64 reads 2
// lanes/bank, b128 uniform 8/bank = hardware minimum, conflict-free.
// global_load_lds dest stays LINEAR; permutation via per-lane SOURCE address.
// Identical bytes, placement-only change: bit-identical output to R7.
__global__ __launch_bounds__(512, 4) void cos_att_main(
    const unsigned char* __restrict__ x8n, const f16* __restrict__ xhT,
    const uint* __restrict__ betaTp, float* __restrict__ out) {
  __shared__ __align__(16) char smem[49152];  // dbuf: 2 x (sXm8 8K + sXmT 16K)
  int bx = blockIdx.x;
  int bc = bx & 63;
  int qp = bx >> 6;  // 0..7
  int q0 = qp * 128;

  int t = threadIdx.x;
  int lane = t & 63;
  int w = t >> 6;  // 0..7
  int l31 = lane & 31;
  int hi = lane >> 5;
  int i_str = (w >> 1) * 32;  // 0,32,64,96
  int m_str = (w & 1) * 32;

  // Xq B-frags (fp8) for this wave's 32 q rows (16 VGPRs)
  i64 xq8[8];
  {
    const unsigned char* base =
        x8n + ((size_t)bc * NTOK + q0 + i_str + l31) * DDIM + hi * 8;
#pragma unroll
    for (int kk = 0; kk < 8; ++kk) xq8[kk] = *(const i64*)(base + kk * 16);
  }

  // stage: LDS dest linear (t*16 / u*16); source permuted so that
  // LDS[R][s] holds global (row 2R+(v&1), chunk v>>1), v = s ^ (R&15).
  auto stage = [&](int mi, int b) {
    int m0 = mi * 64;
    char* ldsm8 = smem + b * 24576;
    char* ldst = ldsm8 + 8192;
    {  // sXm8: [32][256B] paired-row; 512 chunks = 512 threads
      int R = t >> 4;
      int v = (t & 15) ^ (R & 15);
      const unsigned char* gp =
          x8n + ((size_t)bc * NTOK + m0 + 2 * R + (v & 1)) * DDIM +
          (v >> 1) * 16;
      __builtin_amdgcn_global_load_lds((const AS1 uint*)gp,
                                       (AS3 uint*)(ldsm8 + t * 16), 16, 0, 0);
    }
    {  // sXmT: [64][256B] paired-row; 1024 chunks, 2/thread
      const f16* gb = xhT + (size_t)bc * DDIM * NTOK + m0;
#pragma unroll
      for (int j = 0; j < 2; ++j) {
        int u = w * 128 + j * 64 + lane;
        int R = u >> 4;
        int v = (u & 15) ^ (R & 15);
        const f16* gp = gb + (size_t)(2 * R + (v & 1)) * NTOK + (v >> 1) * 8;
        __builtin_amdgcn_global_load_lds((const AS1 uint*)gp,
                                         (AS3 uint*)(ldst + u * 16), 16, 0, 0);
      }
    }
  };

  stage(0, 0);

  f32x16 o[4];
#pragma unroll
  for (int dt = 0; dt < 4; ++dt)
#pragma unroll
    for (int z = 0; z < 16; ++z) o[dt][z] = 0.f;

  for (int mi = 0; mi < 16; ++mi) {
    int b = mi & 1;
    int m0 = mi * 64;
    __syncthreads();  // buf[b] DMA drained; prev reads of buf[1-b] done

    // beta loads FIRST (oldest vmem): f16 pairs, 8 dwords for this subtile
    uint bvp[8];
    {
      const uint* bbase =
          betaTp + (size_t)((m0 + m_str) >> 1) * NTOK + q0 + i_str + l31;
#pragma unroll
      for (int rp = 0; rp < 8; ++rp) {
        int m2l = (rp & 1) + 4 * (rp >> 1) + 2 * hi;
        bvp[rp] = bbase[(size_t)m2l * NTOK];
      }
    }
    if (mi < 15) stage(mi + 1, 1 - b);

    const char* ldsm8 = smem + b * 24576;
    const char* ldst = ldsm8 + 8192;

    // GEMM1 (fp8): S^T = Xm . Xq^T; conflict-free paired-row read
    f32x16 s;
#pragma unroll
    for (int z = 0; z < 16; ++z) s[z] = 0.f;
    {
      int m = m_str + l31;
      int Rr = m >> 1;
      int rxr = Rr & 15;
      int pr = m & 1;
      const char* rowA = ldsm8 + Rr * 256 + hi * 8;
      __builtin_amdgcn_s_setprio(1);
#pragma unroll
      for (int kk = 0; kk < 8; ++kk) {
        i64 a = *(const i64*)(rowA + (((2 * kk + pr) ^ rxr) * 16));
        s = __builtin_amdgcn_mfma_f32_32x32x16_fp8_fp8(a, xq8[kk], s, 0, 0, 0);
      }
      __builtin_amdgcn_s_setprio(0);
    }

    // sigmoid (s dies here), P packed to f16x2 dwords; permlane redistribution
    PFrag b0, b1;
    {
      uint pku[8];
#pragma unroll
      for (int rp = 0; rp < 8; ++rp) {
        f16x2v bh = __builtin_bit_cast(f16x2v, bvp[rp]);
        // betaTp pre-scaled by -log2(e): P = rcp(1 + exp2(b'*cos))
        float e0 = __builtin_amdgcn_exp2f((float)bh[0] * s[2 * rp]);
        float e1 = __builtin_amdgcn_exp2f((float)bh[1] * s[2 * rp + 1]);
        float p0 = __builtin_amdgcn_rcpf(1.0f + e0);
        float p1 = __builtin_amdgcn_rcpf(1.0f + e1);
        pku[rp] = __builtin_bit_cast(uint, __builtin_amdgcn_cvt_pkrtz(p0, p1));
      }
      uint2v r02 = __builtin_amdgcn_permlane32_swap(pku[0], pku[2], false, false);
      uint2v r13 = __builtin_amdgcn_permlane32_swap(pku[1], pku[3], false, false);
      uint2v r46 = __builtin_amdgcn_permlane32_swap(pku[4], pku[6], false, false);
      uint2v r57 = __builtin_amdgcn_permlane32_swap(pku[5], pku[7], false, false);
      b0.u[0] = r02.x;
      b0.u[1] = r13.x;
      b0.u[2] = r02.y;
      b0.u[3] = r13.y;
      b1.u[0] = r46.x;
      b1.u[1] = r57.x;
      b1.u[2] = r46.y;
      b1.u[3] = r57.y;
    }

    // GEMM2 (f16): O^T[d][i] += XmT . P; conflict-free paired-row read
    __builtin_amdgcn_s_setprio(1);
#pragma unroll
    for (int dt = 0; dt < 4; ++dt) {
      int d = dt * 32 + l31;
      int Rd = d >> 1;
      int sl0 = (2 * ((m_str >> 3) + hi) + (d & 1)) ^ (Rd & 15);
      const char* rowT = ldst + Rd * 256;
      f16x8 a0 = *(const f16x8*)(rowT + sl0 * 16);
      f16x8 a1 = *(const f16x8*)(rowT + ((sl0 ^ 4) * 16));
      o[dt] = __builtin_amdgcn_mfma_f32_32x32x16_f16(a0, b0.h, o[dt], 0, 0, 0);
      o[dt] = __builtin_amdgcn_mfma_f32_32x32x16_f16(a1, b1.h, o[dt], 0, 0, 0);
    }
    __builtin_amdgcn_s_setprio(0);
  }

  // epilogue: per 64-row pass, m-half pair-reduce + transpose via LDS.
  // sO logical [64][128] f32, 16B-chunk XOR by (row&7): float4 I/O, <=4-way.
  float* sO = (float*)smem;  // 32 KB < 49152
  int ig = w >> 1;
  int mh = w & 1;
  int row = (ig & 1) * 32 + l31;
  int rb = row & 7;
#pragma unroll
  for (int p = 0; p < 2; ++p) {
    __syncthreads();
    if ((ig >> 1) == p && mh == 0) {
#pragma unroll
      for (int dt = 0; dt < 4; ++dt)
#pragma unroll
        for (int r4 = 0; r4 < 4; ++r4) {
          int c = dt * 8 + 2 * r4 + hi;  // 16B chunk: d = 4*c .. 4*c+3
          float4 v = {o[dt][4 * r4], o[dt][4 * r4 + 1], o[dt][4 * r4 + 2],
                      o[dt][4 * r4 + 3]};
          *(float4*)(sO + row * 128 + ((c ^ rb) * 4)) = v;
        }
    }
    __syncthreads();
    if ((ig >> 1) == p && mh == 1) {
#pragma unroll
      for (int dt = 0; dt < 4; ++dt)
#pragma unroll
        for (int r4 = 0; r4 < 4; ++r4) {
          int c = dt * 8 + 2 * r4 + hi;
          float4* pp = (float4*)(sO + row * 128 + ((c ^ rb) * 4));
          float4 v = *pp;
          v.x += o[dt][4 * r4];
          v.y += o[dt][4 * r4 + 1];
          v.z += o[dt][4 * r4 + 2];
          v.w += o[dt][4 * r4 + 3];
          *pp = v;
        }
    }
    __syncthreads();
    float* og = out + ((size_t)bc * NTOK + q0 + 64 * p) * DDIM;
#pragma unroll
    for (int k = 0; k < 4; ++k) {
      int idx = t + 512 * k;
      int r = idx >> 5;
      int c4 = idx & 31;
      *(float4*)(og + (size_t)r * DDIM + c4 * 4) =
          *(const float4*)(sO + r * 128 + ((c4 ^ (r & 7)) * 4));
    }
  }
}

extern "C" void kernel_launch(void* const* d_in, const int* in_sizes, int n_in,
                              void* d_out, int out_size, void* d_ws,
                              size_t ws_size, hipStream_t stream) {
  const float* x = (const float*)d_in[0];
  const float* beta = (const float*)d_in[1];
  float* out = (float*)d_out;

  char* ws = (char*)d_ws;
  unsigned char* x8n = (unsigned char*)ws;  // 8 MB
  f16* xhT = (f16*)(ws + (8 << 20));        // 16 MB
  uint* betaTp = (uint*)(ws + (24 << 20));  // 2 MB

  prep_fused<<<768, 256, 0, stream>>>(x, beta, x8n, xhT, betaTp);
  cos_att_main<<<512, 512, 0, stream>>>(x8n, xhT, betaTp, out);
}

// Round 11
// 143.960 us; speedup vs baseline: 1.0291x; 1.0084x over previous
//
#include <hip/hip_runtime.h>

#define NTOK 1024
#define DDIM 128

typedef _Float16 f16;
typedef _Float16 f16x2v __attribute__((ext_vector_type(2)));
typedef _Float16 f16x4 __attribute__((ext_vector_type(4)));
typedef _Float16 f16x8 __attribute__((ext_vector_type(8)));
typedef float f32x16 __attribute__((ext_vector_type(16)));
typedef unsigned int uint;
typedef uint uint2v __attribute__((ext_vector_type(2)));
typedef long i64;

union PFrag {
  float f[4];
  uint u[4];
  f16x8 h;
};

#define AS1 __attribute__((address_space(1)))
#define AS3 __attribute__((address_space(3)))
#define NLOG2E -1.44269504f

// ---------------- fused prepass --------------------------------------------
// blocks [0,512):  x -> x8n (normalized fp8) + xhT (f16 transpose) via 4x4
//                  register transpose: vector LDS reads + full-line stores
// blocks [512,640): beta -> betaN [i][ch(32)][hi(2)][rp(8)] dwords so main
//                  reads 8 CONTIGUOUS dwords (2 x dwordx4, imm offsets)
__global__ __launch_bounds__(256) void prep_fused(
    const float* __restrict__ x, const float* __restrict__ beta,
    unsigned char* __restrict__ x8n, f16* __restrict__ xhT,
    uint* __restrict__ betaN) {
  __shared__ __align__(16) char psm[128 * 132 * 2];
  int bx = blockIdx.x;
  int t = threadIdx.x;
  if (bx < 512) {
    f16* sT = (f16*)psm;  // [128 n][132 d-pitch]
    int bc = bx & 63;
    int nt = bx >> 6;
    int n0 = nt * 128;
    const float4* xv = (const float4*)(x + ((size_t)bc * NTOK + n0) * DDIM);
#pragma unroll
    for (int k = 0; k < 16; ++k) {
      int idx = t + 256 * k;
      int row = idx >> 5;
      int c4 = idx & 31;
      float4 v = xv[(size_t)row * 32 + c4];
      float ss = v.x * v.x + v.y * v.y + v.z * v.z + v.w * v.w;
      ss += __shfl_xor(ss, 1);
      ss += __shfl_xor(ss, 2);
      ss += __shfl_xor(ss, 4);
      ss += __shfl_xor(ss, 8);
      ss += __shfl_xor(ss, 16);
      float rn = (ss > 0.f) ? rsqrtf(ss) : 0.f;
      int p01 = __builtin_amdgcn_cvt_pk_fp8_f32(v.x * rn, v.y * rn, 0, false);
      int p03 = __builtin_amdgcn_cvt_pk_fp8_f32(v.z * rn, v.w * rn, p01, true);
      *(int*)(x8n + ((size_t)bc * NTOK + n0 + row) * DDIM + c4 * 4) = p03;
      f16x4 hv = {(f16)v.x, (f16)v.y, (f16)v.z, (f16)v.w};
      *(f16x4*)(sT + row * 132 + c4 * 4) = hv;
    }
    __syncthreads();
    // phase 2: 4x4 register transpose. thread -> (a_low=t&7, b=t>>3),
    // a = a_low + 8*ii. Reads rows 4a+j (d-chunk 4b, b64, conflict-free);
    // writes d-row 4b+j2, n-quad 4a (8B): 8 lanes fill one 64B line/row.
    int a_low = t & 7;
    int b = t >> 3;  // 0..31
    f16* xb = xhT + (size_t)bc * DDIM * NTOK;
#pragma unroll
    for (int ii = 0; ii < 4; ++ii) {
      int a = a_low + 8 * ii;
      uint2 r0 = *(const uint2*)(sT + (4 * a + 0) * 132 + 4 * b);
      uint2 r1 = *(const uint2*)(sT + (4 * a + 1) * 132 + 4 * b);
      uint2 r2 = *(const uint2*)(sT + (4 * a + 2) * 132 + 4 * b);
      uint2 r3 = *(const uint2*)(sT + (4 * a + 3) * 132 + 4 * b);
      uint2 c0, c1, c2, c3;
      c0.x = (r0.x & 0xffffu) | (r1.x << 16);
      c0.y = (r2.x & 0xffffu) | (r3.x << 16);
      c1.x = (r0.x >> 16) | (r1.x & 0xffff0000u);
      c1.y = (r2.x >> 16) | (r3.x & 0xffff0000u);
      c2.x = (r0.y & 0xffffu) | (r1.y << 16);
      c2.y = (r2.y & 0xffffu) | (r3.y << 16);
      c3.x = (r0.y >> 16) | (r1.y & 0xffff0000u);
      c3.y = (r2.y >> 16) | (r3.y & 0xffff0000u);
      size_t base = (size_t)(4 * b) * NTOK + n0 + 4 * a;
      *(uint2*)(xb + base) = c0;
      *(uint2*)(xb + base + NTOK) = c1;
      *(uint2*)(xb + base + 2 * NTOK) = c2;
      *(uint2*)(xb + base + 3 * NTOK) = c3;
    }
  } else {
    // beta part: thread (i, ch) reads 128B contiguous of beta row i,
    // packs 16 pairs (pre-scaled -log2e) into the [hi][rp] order, writes
    // 64B contiguous. Main then loads 8 consecutive dwords per iter.
    int bb = bx - 512;           // 0..127
    int i = bb * 8 + (t >> 5);   // 0..1023
    int ch = t & 31;             // 0..31 (16 m2 per chunk)
    const float* bp = beta + (size_t)i * NTOK + ch * 32;
    float vv[32];
#pragma unroll
    for (int k = 0; k < 8; ++k) {
      float4 v = *(const float4*)(bp + 4 * k);
      vv[4 * k] = v.x;
      vv[4 * k + 1] = v.y;
      vv[4 * k + 2] = v.z;
      vv[4 * k + 3] = v.w;
    }
    uint outw[16];
#pragma unroll
    for (int m2l = 0; m2l < 16; ++m2l) {
      float e0 = vv[2 * m2l] * NLOG2E;
      float e1 = vv[2 * m2l + 1] * NLOG2E;
      int pos = (((m2l >> 1) & 1) << 3) | ((m2l & 1) + 2 * (m2l >> 2));
      outw[pos] = __builtin_bit_cast(uint, __builtin_amdgcn_cvt_pkrtz(e0, e1));
    }
    uint* op = betaN + (size_t)i * 512 + ch * 16;
#pragma unroll
    for (int q = 0; q < 4; ++q) {
      uint4 w = {outw[4 * q], outw[4 * q + 1], outw[4 * q + 2],
                 outw[4 * q + 3]};
      *(uint4*)(op + 4 * q) = w;
    }
  }
}

// ---------------- main ------------------------------------------------------
// R7 champion structure (54.8us, verified) with addressing-only trims:
//  - betas: 2 x dwordx4 from contiguous betaN (imm offsets from one base)
//  - GEMM2 A-reads: precomputed per-thread base + offset dt*4096 (dx = l31&7
//    is dt-invariant, so the slot is a per-thread constant)
//  - GEMM1: XOR slot folded into a 128-aligned base (1 v_xor per read)
// LDS layouts, staging, math, accumulation order: identical to R7.
__global__ __launch_bounds__(512, 4) void cos_att_main(
    const unsigned char* __restrict__ x8n, const f16* __restrict__ xhT,
    const uint* __restrict__ betaN, float* __restrict__ out) {
  __shared__ __align__(128) char smem[49152];  // dbuf: 2 x (sXm8 8K + sXmT 16K)
  int bx = blockIdx.x;
  int bc = bx & 63;
  int qp = bx >> 6;  // 0..7
  int q0 = qp * 128;

  int t = threadIdx.x;
  int lane = t & 63;
  int w = t >> 6;  // 0..7
  int l31 = lane & 31;
  int hi = lane >> 5;
  int i_str = (w >> 1) * 32;  // 0,32,64,96
  int m_str = (w & 1) * 32;

  // Xq B-frags (fp8) for this wave's 32 q rows (16 VGPRs)
  i64 xq8[8];
  {
    const unsigned char* base =
        x8n + ((size_t)bc * NTOK + q0 + i_str + l31) * DDIM + hi * 8;
#pragma unroll
    for (int kk = 0; kk < 8; ++kk) xq8[kk] = *(const i64*)(base + kk * 16);
  }

  auto stage = [&](int mi, int b) {
    int m0 = mi * 64;
    char* ldsm8 = smem + b * 24576;
    char* ldst = ldsm8 + 8192;
    {  // sXm8: 64 rows x 128B fp8, 16B-chunk XOR by (r&7); 512 chunks
      int r = t >> 3;
      int cp = t & 7;
      const unsigned char* gp =
          x8n + ((size_t)bc * NTOK + m0 + r) * DDIM + ((cp ^ (r & 7)) * 16);
      __builtin_amdgcn_global_load_lds((const AS1 uint*)gp,
                                       (AS3 uint*)(ldsm8 + t * 16), 16, 0, 0);
    }
    {  // sXmT: 128 rows x 128B f16, 16B-chunk XOR by (d&7); 2 chunks/thread
      int lr = lane >> 3;
      int cp = lane & 7;
      const f16* gb = xhT + (size_t)bc * DDIM * NTOK + m0;
#pragma unroll
      for (int j = 0; j < 2; ++j) {
        int d = 16 * w + 8 * j + lr;
        int g = cp ^ (d & 7);
        const f16* gp = gb + (size_t)d * NTOK + g * 8;
        __builtin_amdgcn_global_load_lds(
            (const AS1 uint*)gp, (AS3 uint*)(ldst + (16 * w + 8 * j) * 128),
            16, 0, 0);
      }
    }
  };

  stage(0, 0);

  // precomputed bases (loop-invariant):
  // betas: 8 consecutive dwords at bB + mi*32
  const uint* bB =
      betaN + (size_t)(q0 + i_str + l31) * 512 + (m_str >> 5) * 16 + hi * 8;
  // GEMM1: base with XOR slot folded (smem 128-aligned => bits4-6 free)
  int rA = m_str + l31;
  const char* g1b =
      (const char*)((size_t)(smem + rA * 128 + hi * 8) ^ ((size_t)(rA & 7) << 4));
  // GEMM2: slot constants (dx = l31&7 invariant in dt)
  int dx = l31 & 7;
  int g0 = (m_str >> 3) + hi;
  const char* t0b = smem + 8192 + l31 * 128 + ((g0 ^ dx) * 16);
  const char* t1b = smem + 8192 + l31 * 128 + (((g0 + 2) ^ dx) * 16);

  f32x16 o[4];
#pragma unroll
  for (int dt = 0; dt < 4; ++dt)
#pragma unroll
    for (int z = 0; z < 16; ++z) o[dt][z] = 0.f;

  for (int mi = 0; mi < 16; ++mi) {
    int b = mi & 1;
    __syncthreads();  // buf[b] DMA drained; prev reads of buf[1-b] done

    // beta loads FIRST: 2 x dwordx4, contiguous, imm offsets
    uint bvp[8];
    {
      uint4 ba = *(const uint4*)(bB + mi * 32);
      uint4 bb4 = *(const uint4*)(bB + mi * 32 + 4);
      bvp[0] = ba.x; bvp[1] = ba.y; bvp[2] = ba.z; bvp[3] = ba.w;
      bvp[4] = bb4.x; bvp[5] = bb4.y; bvp[6] = bb4.z; bvp[7] = bb4.w;
    }
    if (mi < 15) stage(mi + 1, 1 - b);

    // GEMM1 (fp8): S^T = Xm . Xq^T
    f32x16 s;
#pragma unroll
    for (int z = 0; z < 16; ++z) s[z] = 0.f;
    {
      const char* rowAx = g1b + b * 24576;  // bits4-6 of +b*0x6000 are 0
      __builtin_amdgcn_s_setprio(1);
#pragma unroll
      for (int kk = 0; kk < 8; ++kk) {
        i64 a = *(const i64*)((size_t)rowAx ^ ((size_t)kk << 4));
        s = __builtin_amdgcn_mfma_f32_32x32x16_fp8_fp8(a, xq8[kk], s, 0, 0, 0);
      }
      __builtin_amdgcn_s_setprio(0);
    }

    // sigmoid (s dies here); permlane32_swap redistribution (R7, verified)
    PFrag b0, b1;
    {
      uint pku[8];
#pragma unroll
      for (int rp = 0; rp < 8; ++rp) {
        f16x2v bh = __builtin_bit_cast(f16x2v, bvp[rp]);
        // betaN pre-scaled by -log2(e): P = rcp(1 + exp2(b'*cos))
        float e0 = __builtin_amdgcn_exp2f((float)bh[0] * s[2 * rp]);
        float e1 = __builtin_amdgcn_exp2f((float)bh[1] * s[2 * rp + 1]);
        float p0 = __builtin_amdgcn_rcpf(1.0f + e0);
        float p1 = __builtin_amdgcn_rcpf(1.0f + e1);
        pku[rp] = __builtin_bit_cast(uint, __builtin_amdgcn_cvt_pkrtz(p0, p1));
      }
      uint2v r02 = __builtin_amdgcn_permlane32_swap(pku[0], pku[2], false, false);
      uint2v r13 = __builtin_amdgcn_permlane32_swap(pku[1], pku[3], false, false);
      uint2v r46 = __builtin_amdgcn_permlane32_swap(pku[4], pku[6], false, false);
      uint2v r57 = __builtin_amdgcn_permlane32_swap(pku[5], pku[7], false, false);
      b0.u[0] = r02.x;
      b0.u[1] = r13.x;
      b0.u[2] = r02.y;
      b0.u[3] = r13.y;
      b1.u[0] = r46.x;
      b1.u[1] = r57.x;
      b1.u[2] = r46.y;
      b1.u[3] = r57.y;
    }

    // GEMM2 (f16): O^T[d][i] += XmT . P; base + imm dt*4096
    {
      const char* A0 = t0b + b * 24576;
      const char* A1 = t1b + b * 24576;
      __builtin_amdgcn_s_setprio(1);
#pragma unroll
      for (int dt = 0; dt < 4; ++dt) {
        f16x8 a0 = *(const f16x8*)(A0 + dt * 4096);
        f16x8 a1 = *(const f16x8*)(A1 + dt * 4096);
        o[dt] = __builtin_amdgcn_mfma_f32_32x32x16_f16(a0, b0.h, o[dt], 0, 0, 0);
        o[dt] = __builtin_amdgcn_mfma_f32_32x32x16_f16(a1, b1.h, o[dt], 0, 0, 0);
      }
      __builtin_amdgcn_s_setprio(0);
    }
  }

  // epilogue: per 64-row pass, m-half pair-reduce + transpose via LDS.
  float* sO = (float*)smem;  // 32 KB < 49152
  int ig = w >> 1;
  int mh = w & 1;
  int row = (ig & 1) * 32 + l31;
  int rb = row & 7;
#pragma unroll
  for (int p = 0; p < 2; ++p) {
    __syncthreads();
    if ((ig >> 1) == p && mh == 0) {
#pragma unroll
      for (int dt = 0; dt < 4; ++dt)
#pragma unroll
        for (int r4 = 0; r4 < 4; ++r4) {
          int c = dt * 8 + 2 * r4 + hi;  // 16B chunk: d = 4*c .. 4*c+3
          float4 v = {o[dt][4 * r4], o[dt][4 * r4 + 1], o[dt][4 * r4 + 2],
                      o[dt][4 * r4 + 3]};
          *(float4*)(sO + row * 128 + ((c ^ rb) * 4)) = v;
        }
    }
    __syncthreads();
    if ((ig >> 1) == p && mh == 1) {
#pragma unroll
      for (int dt = 0; dt < 4; ++dt)
#pragma unroll
        for (int r4 = 0; r4 < 4; ++r4) {
          int c = dt * 8 + 2 * r4 + hi;
          float4* pp = (float4*)(sO + row * 128 + ((c ^ rb) * 4));
          float4 v = *pp;
          v.x += o[dt][4 * r4];
          v.y += o[dt][4 * r4 + 1];
          v.z += o[dt][4 * r4 + 2];
          v.w += o[dt][4 * r4 + 3];
          *pp = v;
        }
    }
    __syncthreads();
    float* og = out + ((size_t)bc * NTOK + q0 + 64 * p) * DDIM;
#pragma unroll
    for (int k = 0; k < 4; ++k) {
      int idx = t + 512 * k;
      int r = idx >> 5;
      int c4 = idx & 31;
      *(float4*)(og + (size_t)r * DDIM + c4 * 4) =
          *(const float4*)(sO + r * 128 + ((c4 ^ (r & 7)) * 4));
    }
  }
}

extern "C" void kernel_launch(void* const* d_in, const int* in_sizes, int n_in,
                              void* d_out, int out_size, void* d_ws,
                              size_t ws_size, hipStream_t stream) {
  const float* x = (const float*)d_in[0];
  const float* beta = (const float*)d_in[1];
  float* out = (float*)d_out;

  char* ws = (char*)d_ws;
  unsigned char* x8n = (unsigned char*)ws;  // 8 MB
  f16* xhT = (f16*)(ws + (8 << 20));        // 16 MB
  uint* betaN = (uint*)(ws + (24 << 20));   // 2 MB

  prep_fused<<<640, 256, 0, stream>>>(x, beta, x8n, xhT, betaN);
  cos_att_main<<<512, 512, 0, stream>>>(x8n, xhT, betaN, out);
}